// Round 1
// baseline (413.976 us; speedup 1.0000x reference)
//
#include <hip/hip_runtime.h>
#include <cstdint>
#include <cstddef>

namespace {

constexpr float kScale = 0.03608439182435161f; // 768^-0.5
constexpr float kEps   = 1e-5f;

// workspace offsets (in floats)
constexpr size_t OFF_QK0T = 0;                       // 12*768
constexpr size_t OFF_QBK0 = 9216;                    // 12
constexpr size_t OFF_S    = 16384;                   // 320*12*768 (s0, later s1)
constexpr size_t OFF_QK1  = OFF_S   + 2949120;       // 320*12*768
constexpr size_t OFF_O    = OFF_QK1 + 2949120;       // 320*768
constexpr size_t OFF_U    = OFF_O   + 245760;
constexpr size_t OFF_X    = OFF_U   + 245760;
constexpr size_t OFF_QF1  = OFF_X   + 245760;
constexpr size_t OFF_H1   = OFF_QF1 + 245760;
constexpr size_t OFF_H2   = OFF_H1  + 245760;

__device__ __forceinline__ float Gf(float t){
    float tc = fminf(fmaxf(t, -1.f), 1.f);
    return 0.5f + tc * (1.f - 0.5f * fabsf(tc));
}

__device__ __forceinline__ float blockReduce256(float v, float* red){
    #pragma unroll
    for (int off = 1; off < 64; off <<= 1) v += __shfl_xor(v, off);
    __syncthreads();
    if ((threadIdx.x & 63) == 0) red[threadIdx.x >> 6] = v;
    __syncthreads();
    return red[0] + red[1] + red[2] + red[3];
}

// ---------------------------------------------------------------------------
// k_prep: grid 144 = 12 heads x 12 c-tiles. Computes x0 = LN(token),
// qfull0 = x0@Wq0+bq0 (head slice), qbk0[h], qk0T[h][c] = sum_{d in h} Wk0[c,d]*qfull0[d]
// ---------------------------------------------------------------------------
__global__ __launch_bounds__(256) void k_prep(
        const float* __restrict__ token, const float* __restrict__ g1,
        const float* __restrict__ b1,    const float* __restrict__ Wq0,
        const float* __restrict__ bq0,   const float* __restrict__ Wk0,
        const float* __restrict__ bk0,
        float* __restrict__ qk0T, float* __restrict__ qbk0){
    __shared__ float x0l[768];
    __shared__ float red[8];
    __shared__ float qfp[4][64];
    __shared__ float qfl[64];
    __shared__ float Ws[64][68];
    const int h  = blockIdx.x / 12;
    const int ct = blockIdx.x % 12;
    const int tid = threadIdx.x;

    // LN of score token (identical in every block; cheap)
    float v0 = token[tid], v1 = token[tid+256], v2 = token[tid+512];
    float s = blockReduce256(v0+v1+v2, red);
    float m = s * (1.f/768.f);
    float d0 = v0-m, d1 = v1-m, d2 = v2-m;
    float qv = blockReduce256(d0*d0+d1*d1+d2*d2, red);
    float rs = rsqrtf(qv*(1.f/768.f) + kEps);
    x0l[tid]     = d0*rs*g1[tid]     + b1[tid];
    x0l[tid+256] = d1*rs*g1[tid+256] + b1[tid+256];
    x0l[tid+512] = d2*rs*g1[tid+512] + b1[tid+512];
    __syncthreads();

    // qfull0 for this head's 64 d (4 c-partials per d)
    {
        int dl = tid & 63, part = tid >> 6;
        int d = h*64 + dl;
        float a = 0.f;
        for (int c = part*192; c < part*192 + 192; ++c)
            a += x0l[c] * Wq0[(size_t)c*768 + d];
        qfp[part][dl] = a;
    }
    __syncthreads();
    if (tid < 64){
        int d = h*64 + tid;
        qfl[tid] = qfp[0][tid]+qfp[1][tid]+qfp[2][tid]+qfp[3][tid] + bq0[d];
    }
    __syncthreads();
    if (ct == 0 && tid < 64){
        float v = qfl[tid] * bk0[h*64 + tid];
        #pragma unroll
        for (int off = 1; off < 64; off <<= 1) v += __shfl_xor(v, off);
        if (tid == 0) qbk0[h] = v;
    }
    // qk0T for this block's 64 c
    #pragma unroll
    for (int i = 0; i < 4; ++i){
        int f = tid + i*256; int cl = f >> 4, dd = (f & 15)*4;
        float4 v = *(const float4*)(Wk0 + (size_t)(ct*64+cl)*768 + h*64 + dd);
        *(float4*)&Ws[cl][dd] = v;
    }
    __syncthreads();
    {
        int cl = tid >> 2, part = tid & 3;
        float a = 0.f;
        #pragma unroll
        for (int jj = 0; jj < 16; ++jj){
            int dd = part*16 + jj;
            a += Ws[cl][dd] * qfl[dd];
        }
        a += __shfl_xor(a, 1); a += __shfl_xor(a, 2);
        if (part == 0) qk0T[h*768 + ct*64 + cl] = a;
    }
}

// ---------------------------------------------------------------------------
// k_pool: grid 320 (one ROI each). PrRoI pooling (row/col-skipped) -> P[16][768]
// in LDS -> branch-0 logits/softmax -> s0[r][12][768]
// ---------------------------------------------------------------------------
__global__ __launch_bounds__(256) void k_pool(
        const float* __restrict__ feats, const float* __restrict__ boxes,
        const float* __restrict__ qk0T,  const float* __restrict__ qbk0g,
        float* __restrict__ s0){
    __shared__ float P2[16][776];
    __shared__ float wxp[24][4];
    __shared__ float wyp[24][4];
    __shared__ float logitsL[12][17];
    __shared__ float attnT[16][12];
    __shared__ int   rng[4];
    __shared__ float areaInvS;
    const int r = blockIdx.x, tid = threadIdx.x;

    float bx0 = boxes[r*4+0]*24.f, by0 = boxes[r*4+1]*24.f;
    float bx1 = boxes[r*4+2]*24.f, by1 = boxes[r*4+3]*24.f;
    float bw = (bx1-bx0)*0.25f, bh = (by1-by0)*0.25f;
    if (tid == 0){
        int hlo = (int)floorf(by0) - 1; if (hlo < 0) hlo = 0;
        int hhi = (int)floorf(by1) + 1; if (hhi > 23) hhi = 23;
        int wlo = (int)floorf(bx0) - 1; if (wlo < 0) wlo = 0;
        int whi = (int)floorf(bx1) + 1; if (whi > 23) whi = 23;
        rng[0] = hlo; rng[1] = hhi; rng[2] = wlo >> 2; rng[3] = whi >> 2;
        areaInvS = 1.f / fmaxf(bw*bh, 1e-8f);
    }
    if (tid < 24){
        int w = tid;
        #pragma unroll
        for (int q = 0; q < 4; ++q){
            float e0 = bx0 + q*bw, e1 = e0 + bw;
            wxp[w][q] = Gf(e1 - (float)w) - Gf(e0 - (float)w);
        }
    } else if (tid < 48){
        int hh = tid - 24;
        #pragma unroll
        for (int p = 0; p < 4; ++p){
            float e0 = by0 + p*bh, e1 = e0 + bh;
            wyp[hh][p] = Gf(e1 - (float)hh) - Gf(e0 - (float)hh);
        }
    }
    __syncthreads();
    const int hlo = rng[0], hhi = rng[1], w4lo = rng[2], w4hi = rng[3];
    const float aInv = areaInvS;
    const int j = tid & 7;
    const int cbase = tid >> 3;

    for (int cg = 0; cg < 24; ++cg){
        int c = cg*32 + cbase;
        const float* fb = feats + ((size_t)r*768 + c)*576;
        float acc[16];
        #pragma unroll
        for (int k = 0; k < 16; ++k) acc[k] = 0.f;
        for (int hh = hlo + j; hh <= hhi; hh += 8){
            const float* rowp = fb + hh*24;
            float z[4] = {0.f,0.f,0.f,0.f};
            for (int w4 = w4lo; w4 <= w4hi; ++w4){
                float4 xv = *(const float4*)(rowp + w4*4);
                float xa[4] = {xv.x, xv.y, xv.z, xv.w};
                #pragma unroll
                for (int k = 0; k < 4; ++k){
                    float4 wv = *(const float4*)&wxp[w4*4+k][0];
                    z[0] += wv.x*xa[k]; z[1] += wv.y*xa[k];
                    z[2] += wv.z*xa[k]; z[3] += wv.w*xa[k];
                }
            }
            float4 wyv = *(const float4*)&wyp[hh][0];
            float wya[4] = {wyv.x, wyv.y, wyv.z, wyv.w};
            #pragma unroll
            for (int p = 0; p < 4; ++p)
                #pragma unroll
                for (int q = 0; q < 4; ++q)
                    acc[p*4+q] += wya[p]*z[q];
        }
        #pragma unroll
        for (int k = 0; k < 16; ++k){
            acc[k] += __shfl_xor(acc[k], 1);
            acc[k] += __shfl_xor(acc[k], 2);
            acc[k] += __shfl_xor(acc[k], 4);
        }
        P2[j][c]   = acc[j]   * aInv;
        P2[j+8][c] = acc[j+8] * aInv;
    }
    __syncthreads();

    // logits0[h][t]
    if (tid < 192){
        int h = tid >> 4, t = tid & 15;
        float a = qbk0g[h];
        const float* qrow = qk0T + h*768;
        #pragma unroll 4
        for (int c4 = 0; c4 < 192; ++c4){
            float4 qv = *(const float4*)(qrow + c4*4);
            float4 pv = *(const float4*)&P2[t][c4*4];
            a += qv.x*pv.x + qv.y*pv.y + qv.z*pv.z + qv.w*pv.w;
        }
        logitsL[h][t] = a * kScale;
    }
    __syncthreads();
    if (tid < 12){
        float mx = -1e30f;
        for (int t = 0; t < 16; ++t) mx = fmaxf(mx, logitsL[tid][t]);
        float ss = 0.f;
        for (int t = 0; t < 16; ++t){
            float e = expf(logitsL[tid][t] - mx);
            attnT[t][tid] = e; ss += e;
        }
        float rsn = 1.f/ss;
        for (int t = 0; t < 16; ++t) attnT[t][tid] *= rsn;
    }
    __syncthreads();
    // s0[h][c] = sum_t attn[h][t]*P[t][c]
    #pragma unroll
    for (int s3 = 0; s3 < 3; ++s3){
        int c = tid + s3*256;
        float a12[12];
        #pragma unroll
        for (int h = 0; h < 12; ++h) a12[h] = 0.f;
        #pragma unroll
        for (int t = 0; t < 16; ++t){
            float x = P2[t][c];
            float4 a0 = *(const float4*)&attnT[t][0];
            float4 a1 = *(const float4*)&attnT[t][4];
            float4 a2 = *(const float4*)&attnT[t][8];
            a12[0] += a0.x*x; a12[1] += a0.y*x; a12[2]  += a0.z*x; a12[3]  += a0.w*x;
            a12[4] += a1.x*x; a12[5] += a1.y*x; a12[6]  += a1.z*x; a12[7]  += a1.w*x;
            a12[8] += a2.x*x; a12[9] += a2.y*x; a12[10] += a2.z*x; a12[11] += a2.w*x;
        }
        #pragma unroll
        for (int h = 0; h < 12; ++h)
            s0[((size_t)r*12 + h)*768 + c] = a12[h];
    }
}

// ---------------------------------------------------------------------------
// k_gemm: C[m][n] = act(bias[n] + sum_k A[m,k]*B[k,n]), M=320,N=768,K=768
// HG: A row = (m*12 + n/64)*768 (head-gathered s buffer)
// grid (20, 12), 16x64 tile
// ---------------------------------------------------------------------------
template<int HG, int RELU>
__global__ __launch_bounds__(256) void k_gemm(
        const float* __restrict__ A, const float* __restrict__ B,
        const float* __restrict__ bias, float* __restrict__ C){
    __shared__ float As[16][68];
    __shared__ float Bs[64][68];
    const int m0 = blockIdx.x * 16;
    const int n0 = blockIdx.y * 64;
    const int h  = blockIdx.y;
    const int tid = threadIdx.x;
    const int tn = tid & 15, tm = tid >> 4;
    float acc[4] = {0.f,0.f,0.f,0.f};

    for (int kt = 0; kt < 768; kt += 64){
        {
            int ml = tid >> 4, kk = (tid & 15)*4;
            const float* src = HG ? (A + ((size_t)(m0+ml)*12 + h)*768 + kt + kk)
                                  : (A + (size_t)(m0+ml)*768 + kt + kk);
            *(float4*)&As[ml][kk] = *(const float4*)src;
        }
        #pragma unroll
        for (int i = 0; i < 4; ++i){
            int f = tid + i*256;
            int kl = f >> 4, nn = (f & 15)*4;
            *(float4*)&Bs[kl][nn] =
                *(const float4*)(B + (size_t)(kt+kl)*768 + n0 + nn);
        }
        __syncthreads();
        #pragma unroll
        for (int k4 = 0; k4 < 16; ++k4){
            float4 av = *(const float4*)&As[tm][k4*4];
            float aa[4] = {av.x, av.y, av.z, av.w};
            #pragma unroll
            for (int jj = 0; jj < 4; ++jj){
                float4 bv = *(const float4*)&Bs[k4*4+jj][tn*4];
                acc[0] += aa[jj]*bv.x; acc[1] += aa[jj]*bv.y;
                acc[2] += aa[jj]*bv.z; acc[3] += aa[jj]*bv.w;
            }
        }
        __syncthreads();
    }
    int n = n0 + tn*4;
    float4 bb = *(const float4*)(bias + n);
    acc[0] += bb.x; acc[1] += bb.y; acc[2] += bb.z; acc[3] += bb.w;
    if (RELU){
        acc[0] = fmaxf(acc[0],0.f); acc[1] = fmaxf(acc[1],0.f);
        acc[2] = fmaxf(acc[2],0.f); acc[3] = fmaxf(acc[3],0.f);
    }
    float4 outv; outv.x = acc[0]; outv.y = acc[1]; outv.z = acc[2]; outv.w = acc[3];
    *(float4*)(C + (size_t)(m0+tm)*768 + n) = outv;
}

// ---------------------------------------------------------------------------
// k_qk1: qk1[r][h][c] = sum_{dl<64} qfull1[r, h*64+dl] * Wk1[c, h*64+dl]
// grid (10, 12, 12): 32 r x 64 c per block, K=64
// ---------------------------------------------------------------------------
__global__ __launch_bounds__(256) void k_qk1(
        const float* __restrict__ qf1, const float* __restrict__ Wk1,
        float* __restrict__ qk1){
    __shared__ float As[32][68];
    __shared__ float Bs[64][68]; // [d][c]
    const int r0 = blockIdx.x * 32, h = blockIdx.y, c0 = blockIdx.z * 64;
    const int tid = threadIdx.x;
    #pragma unroll
    for (int i = 0; i < 2; ++i){
        int f = tid + i*256; int ml = f >> 4, kk = (f & 15)*4;
        *(float4*)&As[ml][kk] =
            *(const float4*)(qf1 + (size_t)(r0+ml)*768 + h*64 + kk);
    }
    #pragma unroll
    for (int i = 0; i < 4; ++i){
        int f = tid + i*256; int cl = f >> 4, dd = (f & 15)*4;
        float4 v = *(const float4*)(Wk1 + (size_t)(c0+cl)*768 + h*64 + dd);
        Bs[dd+0][cl] = v.x; Bs[dd+1][cl] = v.y;
        Bs[dd+2][cl] = v.z; Bs[dd+3][cl] = v.w;
    }
    __syncthreads();
    const int tn = tid & 15, tm = tid >> 4;
    float acc0[4] = {0.f,0.f,0.f,0.f};
    float acc1[4] = {0.f,0.f,0.f,0.f};
    #pragma unroll
    for (int k4 = 0; k4 < 16; ++k4){
        float4 av0 = *(const float4*)&As[tm*2+0][k4*4];
        float4 av1 = *(const float4*)&As[tm*2+1][k4*4];
        float a0a[4] = {av0.x, av0.y, av0.z, av0.w};
        float a1a[4] = {av1.x, av1.y, av1.z, av1.w};
        #pragma unroll
        for (int jj = 0; jj < 4; ++jj){
            float4 bv = *(const float4*)&Bs[k4*4+jj][tn*4];
            acc0[0] += a0a[jj]*bv.x; acc0[1] += a0a[jj]*bv.y;
            acc0[2] += a0a[jj]*bv.z; acc0[3] += a0a[jj]*bv.w;
            acc1[0] += a1a[jj]*bv.x; acc1[1] += a1a[jj]*bv.y;
            acc1[2] += a1a[jj]*bv.z; acc1[3] += a1a[jj]*bv.w;
        }
    }
    float4 o0; o0.x=acc0[0]; o0.y=acc0[1]; o0.z=acc0[2]; o0.w=acc0[3];
    float4 o1; o1.x=acc1[0]; o1.y=acc1[1]; o1.z=acc1[2]; o1.w=acc1[3];
    *(float4*)(qk1 + ((size_t)(r0+tm*2+0)*12 + h)*768 + c0 + tn*4) = o0;
    *(float4*)(qk1 + ((size_t)(r0+tm*2+1)*12 + h)*768 + c0 + tn*4) = o1;
}

// ---------------------------------------------------------------------------
// k_attn1: grid 320 (one ROI). Branch-1 logits/softmax/s1 against template.
// template natural layout [c][t] (t contiguous, 64).
// ---------------------------------------------------------------------------
__global__ __launch_bounds__(256) void k_attn1(
        const float* __restrict__ tmpl, const float* __restrict__ qf1,
        const float* __restrict__ bk1,  const float* __restrict__ qk1,
        float* __restrict__ s1){
    __shared__ float Tc[192][68];
    __shared__ float logitsT[64][13];
    __shared__ float attnH[12][64];
    __shared__ float qbk[12];
    const int r = blockIdx.x, tid = threadIdx.x;
    const float* tp = tmpl + (size_t)r*768*64;

    if (tid < 192){
        int h = tid >> 4, pp = tid & 15;
        float v = 0.f;
        #pragma unroll
        for (int jj = 0; jj < 4; ++jj){
            int d = h*64 + pp*4 + jj;
            v += bk1[d] * qf1[(size_t)r*768 + d];
        }
        v += __shfl_xor(v,1); v += __shfl_xor(v,2);
        v += __shfl_xor(v,4); v += __shfl_xor(v,8);
        if (pp == 0) qbk[h] = v;
    }
    __syncthreads();
    float lacc[3];
    #pragma unroll
    for (int s = 0; s < 3; ++s){
        int task = tid + s*256;
        lacc[s] = qbk[task >> 6];
    }
    // phase A: logits
    for (int cb = 0; cb < 4; ++cb){
        #pragma unroll
        for (int i = 0; i < 12; ++i){
            int f = tid + i*256; int cl = f >> 4, t4 = (f & 15)*4;
            *(float4*)&Tc[cl][t4] =
                *(const float4*)(tp + (size_t)(cb*192 + cl)*64 + t4);
        }
        __syncthreads();
        #pragma unroll
        for (int s = 0; s < 3; ++s){
            int task = tid + s*256;
            int h = task >> 6, t = task & 63;
            const float* qrow = qk1 + ((size_t)r*12 + h)*768 + cb*192;
            float a = 0.f;
            #pragma unroll 4
            for (int c4 = 0; c4 < 48; ++c4){
                float4 qv = *(const float4*)(qrow + c4*4);
                a += qv.x*Tc[c4*4+0][t] + qv.y*Tc[c4*4+1][t]
                   + qv.z*Tc[c4*4+2][t] + qv.w*Tc[c4*4+3][t];
            }
            lacc[s] += a;
        }
        __syncthreads();
    }
    #pragma unroll
    for (int s = 0; s < 3; ++s){
        int task = tid + s*256;
        logitsT[task & 63][task >> 6] = lacc[s] * kScale;
    }
    __syncthreads();
    if (tid < 12){
        float mx = -1e30f;
        for (int t = 0; t < 64; ++t) mx = fmaxf(mx, logitsT[t][tid]);
        float ss = 0.f;
        for (int t = 0; t < 64; ++t){
            float e = expf(logitsT[t][tid] - mx);
            attnH[tid][t] = e; ss += e;
        }
        float rsn = 1.f/ss;
        for (int t = 0; t < 64; ++t) attnH[tid][t] *= rsn;
    }
    __syncthreads();
    // phase B: s1[h][c]
    for (int cb = 0; cb < 4; ++cb){
        #pragma unroll
        for (int i = 0; i < 12; ++i){
            int f = tid + i*256; int cl = f >> 4, t4 = (f & 15)*4;
            *(float4*)&Tc[cl][t4] =
                *(const float4*)(tp + (size_t)(cb*192 + cl)*64 + t4);
        }
        __syncthreads();
        if (tid < 192){
            float4 trow[16];
            #pragma unroll
            for (int t4 = 0; t4 < 16; ++t4)
                trow[t4] = *(const float4*)&Tc[tid][t4*4];
            int c = cb*192 + tid;
            #pragma unroll
            for (int h = 0; h < 12; ++h){
                float a = 0.f;
                #pragma unroll
                for (int t4 = 0; t4 < 16; ++t4){
                    float4 avv = *(const float4*)&attnH[h][t4*4];
                    float4 tv = trow[t4];
                    a += avv.x*tv.x + avv.y*tv.y + avv.z*tv.z + avv.w*tv.w;
                }
                s1[((size_t)r*12 + h)*768 + c] = a;
            }
        }
        __syncthreads();
    }
}

// ---------------------------------------------------------------------------
// k_lnmix: grid 32 (one b). LN(u[n,b,:]) with ln2 params, then N-mix with Wmix.
// ---------------------------------------------------------------------------
__global__ __launch_bounds__(256) void k_lnmix(
        const float* __restrict__ u, const float* __restrict__ g,
        const float* __restrict__ bta, const float* __restrict__ Wmix,
        const float* __restrict__ bmix, float* __restrict__ xout){
    __shared__ float lnl[10][768];
    __shared__ float red[8];
    __shared__ float wm[100];
    __shared__ float bm[10];
    const int b = blockIdx.x, tid = threadIdx.x;
    if (tid < 100) wm[tid] = Wmix[tid];
    if (tid < 10)  bm[tid] = bmix[tid];
    for (int n = 0; n < 10; ++n){
        const float* row = u + (size_t)(n*32 + b)*768;
        float v0 = row[tid], v1 = row[tid+256], v2 = row[tid+512];
        float s = blockReduce256(v0+v1+v2, red);
        float m = s * (1.f/768.f);
        float d0 = v0-m, d1 = v1-m, d2 = v2-m;
        float qv = blockReduce256(d0*d0+d1*d1+d2*d2, red);
        float rs = rsqrtf(qv*(1.f/768.f) + kEps);
        lnl[n][tid]     = d0*rs*g[tid]     + bta[tid];
        lnl[n][tid+256] = d1*rs*g[tid+256] + bta[tid+256];
        lnl[n][tid+512] = d2*rs*g[tid+512] + bta[tid+512];
    }
    __syncthreads();
    #pragma unroll
    for (int s3 = 0; s3 < 3; ++s3){
        int c = tid + s3*256;
        float col[10];
        #pragma unroll
        for (int n = 0; n < 10; ++n) col[n] = lnl[n][c];
        #pragma unroll
        for (int np = 0; np < 10; ++np){
            float a = bm[np];
            #pragma unroll
            for (int n = 0; n < 10; ++n) a += col[n]*wm[n*10+np];
            xout[(size_t)(np*32 + b)*768 + c] = a;
        }
    }
}

// ---------------------------------------------------------------------------
// k_head: out[r] = b3 + sum_e h2[r][e]*W3[e]
// ---------------------------------------------------------------------------
__global__ __launch_bounds__(256) void k_head(
        const float* __restrict__ h2v, const float* __restrict__ W3,
        const float* __restrict__ b3, float* __restrict__ out){
    __shared__ float red[8];
    const int r = blockIdx.x, tid = threadIdx.x;
    const float* row = h2v + (size_t)r*768;
    float a = row[tid]*W3[tid] + row[tid+256]*W3[tid+256] + row[tid+512]*W3[tid+512];
    a = blockReduce256(a, red);
    if (tid == 0) out[r] = a + b3[0];
}

} // anonymous namespace

extern "C" void kernel_launch(void* const* d_in, const int* in_sizes, int n_in,
                              void* d_out, int out_size, void* d_ws, size_t ws_size,
                              hipStream_t stream){
    const float* feats = (const float*)d_in[0];
    const float* tmpl  = (const float*)d_in[1];
    const float* boxes = (const float*)d_in[2];
    const float* token = (const float*)d_in[3];
    const float* ln1g  = (const float*)d_in[4];
    const float* ln1b  = (const float*)d_in[5];
    const float* Wq    = (const float*)d_in[6];
    const float* bq    = (const float*)d_in[7];
    const float* Wk    = (const float*)d_in[8];
    const float* bk    = (const float*)d_in[9];
    const float* Wv    = (const float*)d_in[10];
    const float* bv    = (const float*)d_in[11];
    const float* Wo    = (const float*)d_in[12];
    const float* bo    = (const float*)d_in[13];
    const float* ln2g  = (const float*)d_in[14];
    const float* ln2b  = (const float*)d_in[15];
    const float* Wmix  = (const float*)d_in[16];
    const float* bmix  = (const float*)d_in[17];
    const float* W1    = (const float*)d_in[18];
    const float* b1v   = (const float*)d_in[19];
    const float* W2    = (const float*)d_in[20];
    const float* b2v   = (const float*)d_in[21];
    const float* W3    = (const float*)d_in[22];
    const float* b3v   = (const float*)d_in[23];
    float* ws  = (float*)d_ws;
    float* out = (float*)d_out;

    float* qk0T = ws + OFF_QK0T;
    float* qbk0 = ws + OFF_QBK0;
    float* sbuf = ws + OFF_S;
    float* qk1  = ws + OFF_QK1;
    float* obuf = ws + OFF_O;
    float* ubuf = ws + OFF_U;
    float* xbuf = ws + OFF_X;
    float* qf1  = ws + OFF_QF1;
    float* h1b  = ws + OFF_H1;
    float* h2b  = ws + OFF_H2;

    const size_t MO = 589824; // 768*768

    k_prep<<<144, 256, 0, stream>>>(token, ln1g, ln1b, Wq, bq, Wk, bk, qk0T, qbk0);
    k_pool<<<320, 256, 0, stream>>>(feats, boxes, qk0T, qbk0, sbuf);
    k_gemm<1,0><<<dim3(20,12), 256, 0, stream>>>(sbuf, Wv, bv, obuf);
    k_gemm<0,0><<<dim3(20,12), 256, 0, stream>>>(obuf, Wo, bo, ubuf);
    k_lnmix<<<32, 256, 0, stream>>>(ubuf, ln2g, ln2b, Wmix, bmix, xbuf);
    k_gemm<0,0><<<dim3(20,12), 256, 0, stream>>>(xbuf, Wq + MO, bq + 768, qf1);
    k_qk1<<<dim3(10,12,12), 256, 0, stream>>>(qf1, Wk + MO, qk1);
    k_attn1<<<320, 256, 0, stream>>>(tmpl, qf1, bk + 768, qk1, sbuf);
    k_gemm<1,0><<<dim3(20,12), 256, 0, stream>>>(sbuf, Wv + MO, bv + 768, obuf);
    k_gemm<0,0><<<dim3(20,12), 256, 0, stream>>>(obuf, Wo + MO, bo + 768, ubuf);
    k_lnmix<<<32, 256, 0, stream>>>(ubuf, ln2g + 768, ln2b + 768, Wmix + 100, bmix + 10, xbuf);
    k_gemm<0,1><<<dim3(20,12), 256, 0, stream>>>(xbuf, W1, b1v, h1b);
    k_gemm<0,1><<<dim3(20,12), 256, 0, stream>>>(h1b, W2, b2v, h2b);
    k_head<<<320, 256, 0, stream>>>(h2b, W3, b3v, out);
}